// Round 3
// baseline (285.150 us; speedup 1.0000x reference)
//
#include <hip/hip_runtime.h>

#define BATCH 32
#define LANCH 8400
#define NCLS  80
#define NGT   64
#define TOPK  13
#define NCHUNK 33          // ceil(8400/256)
#define NQ4   2100         // uint4 words per metric row (8400/4)
#define QSEG  525          // uint4 words per wave quarter (2100/4)
#define NW64  132          // u64 words of ing-bits per row (8448 bits)

// ---- shared per-block GT data ----
struct GtLds {
  float4 box[NGT];
  float  ga[NGT], gcx[NGT], gcy[NGT], atg[NGT], padf[NGT];
  int    lab[NGT];
};

__device__ __forceinline__ void load_gt(GtLds& s, int b,
    const float* gt_bboxes, const int* gt_labels, const float* pad_mask, int t)
{
  if (t < NGT) {
    float4 g = reinterpret_cast<const float4*>(gt_bboxes)[b * NGT + t];
    s.box[t] = g;
    float gw = g.z - g.x, gh = g.w - g.y;
    s.ga[t]  = gw * gh;
    s.gcx[t] = (g.x + g.z) * 0.5f;
    s.gcy[t] = (g.y + g.w) * 0.5f;
    s.atg[t] = atanf(gw / gh);
    s.padf[t] = pad_mask[b * NGT + t];
    s.lab[t]  = gt_labels[b * NGT + t];
  }
}

// clipped CIoU (no ing/pad factors) — shared by all kernels so recompute matches
__device__ __forceinline__ float ciou_core(
    float4 pb, float pa, float pcx, float pcy, float atp,
    float4 gb, float ga, float gcx, float gcy, float atg)
{
  float iw = fmaxf(fminf(gb.z, pb.z) - fmaxf(gb.x, pb.x), 0.f);
  float ih = fmaxf(fminf(gb.w, pb.w) - fmaxf(gb.y, pb.y), 0.f);
  float inter = iw * ih;
  float uni   = ga + pa - inter;
  float iou   = inter / uni;
  float wi = fmaxf(fmaxf(gb.z, pb.z) - fminf(gb.x, pb.x), 0.f);
  float hi = fmaxf(fmaxf(gb.w, pb.w) - fminf(gb.y, pb.y), 0.f);
  float diag2 = wi * wi + hi * hi + 1e-7f;
  float dx = gcx - pcx, dy = gcy - pcy;
  float diou = iou - (dx * dx + dy * dy) / diag2;
  float dat = atg - atp;
  float v = 0.40528473456935109f * dat * dat;     // 4/pi^2
  float alpha = v / (1.f - iou + v + 1e-7f);
  return fmaxf(diou - alpha * v, 0.f);            // nan_to_num + clip>=0
}

__device__ __forceinline__ float masked_ciou(
    float4 pb, float pa, float pcx, float pcy, float atp, float2 cc,
    float4 gb, float ga, float gcx, float gcy, float atg, float padf)
{
  float ltrb = fminf(fminf(cc.x - gb.x, cc.y - gb.y),
                     fminf(gb.z - cc.x, gb.w - cc.y));
  if (!(ltrb > 1e-9f) || padf == 0.f) return 0.f;
  return ciou_core(pb, pa, pcx, pcy, atp, gb, ga, gcx, gcy, atg);
}

__device__ __forceinline__ unsigned long long umax64(unsigned long long a,
                                                     unsigned long long b)
{ return a > b ? a : b; }

__device__ __forceinline__ unsigned long long mkkey(unsigned int bits, int l)
{ return ((unsigned long long)bits << 32) | (unsigned int)(0x7FFFFFFF - l); }

// ---------------- K1a: metrics + packed ing-bits + mask64 zero ----------------
__global__ __launch_bounds__(256) void k_pairs(
    const float* __restrict__ pred_scores,
    const float* __restrict__ pred_bboxes,
    const float* __restrict__ centers,
    const int*   __restrict__ gt_labels,
    const float* __restrict__ gt_bboxes,
    const float* __restrict__ pad_mask,
    float*       __restrict__ ws_met,
    unsigned long long* __restrict__ ws_ing,
    unsigned long long* __restrict__ mask64,
    float*       __restrict__ ws_mm,
    float*       __restrict__ ws_mi)
{
  __shared__ GtLds s;
  const int b = blockIdx.y, t = threadIdx.x;
  load_gt(s, b, gt_bboxes, gt_labels, pad_mask, t);
  if (blockIdx.x == 0) {                 // zero per-gt maxima once per batch
    if (t < NGT)            ws_mm[b * NGT + t] = 0.f;
    else if (t < 2 * NGT)   ws_mi[b * NGT + t - NGT] = 0.f;
  }
  __syncthreads();
  const int  l   = blockIdx.x * 256 + t;
  const bool act = (l < LANCH);
  const int  lc  = act ? l : (LANCH - 1);

  const float4 pb = reinterpret_cast<const float4*>(pred_bboxes)[(size_t)b * LANCH + lc];
  const float2 cc = reinterpret_cast<const float2*>(centers)[lc];
  const float pw = pb.z - pb.x, ph = pb.w - pb.y;
  const float pa = pw * ph;
  const float pcx = (pb.x + pb.z) * 0.5f, pcy = (pb.y + pb.w) * 0.5f;
  const float atp = atanf(pw / ph);
  const float* srow = pred_scores + ((size_t)b * LANCH + lc) * NCLS;

  if (act) mask64[(size_t)b * LANCH + l] = 0ull;   // zero for k_topk atomicOr
  const int word = blockIdx.x * 4 + (t >> 6);      // 0..131

  for (int g = 0; g < NGT; ++g) {
    if (s.padf[g] == 0.f) break;                   // pad mask is a prefix
    const float4 gb = s.box[g];
    float ltrb = fminf(fminf(cc.x - gb.x, cc.y - gb.y),
                       fminf(gb.z - cc.x, gb.w - cc.y));
    bool ing = act && (ltrb > 1e-9f);
    unsigned long long bal = __ballot(ing);
    if ((t & 63) == 0)
      ws_ing[(size_t)(b * NGT + g) * NW64 + word] = bal;
    float met = 0.f;
    if (ing) {
      float io = ciou_core(pb, pa, pcx, pcy, atp,
                           gb, s.ga[g], s.gcx[g], s.gcy[g], s.atg[g]);
      float t2 = io * io;
      met = srow[s.lab[g]] * (t2 * t2 * t2);       // score^1 * iou^6
    }
    if (act) ws_met[(size_t)(b * NGT + g) * LANCH + l] = met;
  }
}

// ---------------- K1b: exact top-13 per (b,gt) row -> atomicOr into mask64 ----------------
__global__ __launch_bounds__(256) void k_topk(
    const float* __restrict__ ws_met,
    const unsigned long long* __restrict__ ws_ing,
    unsigned long long* __restrict__ mask64,
    const float* __restrict__ pad_mask)
{
  const int bg = blockIdx.x;
  if (pad_mask[bg] == 0.f) return;
  __shared__ uint4 s_b4[NQ4];
  __shared__ unsigned long long s_seg[4];
  __shared__ int s_top[TOPK];
  __shared__ unsigned long long s_ingr[NW64];
  unsigned int* s_bits = reinterpret_cast<unsigned int*>(s_b4);
  const int t = threadIdx.x;
  const uint4* mrow = reinterpret_cast<const uint4*>(ws_met + (size_t)bg * LANCH);
  for (int j = t; j < NQ4; j += 256) s_b4[j] = mrow[j];
  if (t < NW64) s_ingr[t] = ws_ing[(size_t)bg * NW64 + t];
  __syncthreads();

  const int w = t >> 6, lane = t & 63;
  unsigned long long key = 0;
  for (int i = lane; i < QSEG; i += 64) {
    uint4 u = s_b4[w * QSEG + i];
    int l0 = (w * QSEG + i) * 4;
    key = umax64(key, mkkey(u.x, l0));
    key = umax64(key, mkkey(u.y, l0 + 1));
    key = umax64(key, mkkey(u.z, l0 + 2));
    key = umax64(key, mkkey(u.w, l0 + 3));
  }
  #pragma unroll
  for (int off = 32; off > 0; off >>= 1) {
    unsigned long long o =
      (((unsigned long long)(unsigned int)__shfl_down((unsigned int)(key >> 32), off)) << 32)
      | (unsigned int)__shfl_down((unsigned int)(key & 0xFFFFFFFFu), off);
    if (o > key) key = o;
  }
  if (lane == 0) s_seg[w] = key;
  __syncthreads();

  for (int it = 0; it < TOPK; ++it) {
    if (t == 0) {
      unsigned long long k = s_seg[0];
      if (s_seg[1] > k) k = s_seg[1];
      if (s_seg[2] > k) k = s_seg[2];
      if (s_seg[3] > k) k = s_seg[3];
      int l = 0x7FFFFFFF - (int)(unsigned int)(k & 0xFFFFFFFFu);
      s_top[it] = l;
      s_bits[l] = 0xFFFFFFFFu;          // sentinel (never a valid non-neg float)
    }
    __syncthreads();
    const int ow = (s_top[it] >> 2) / QSEG;   // owner wave's quarter
    if (w == ow) {
      unsigned long long k2 = 0;
      for (int i = lane; i < QSEG; i += 64) {
        uint4 u = s_b4[w * QSEG + i];
        int l0 = (w * QSEG + i) * 4;
        if (u.x != 0xFFFFFFFFu) k2 = umax64(k2, mkkey(u.x, l0));
        if (u.y != 0xFFFFFFFFu) k2 = umax64(k2, mkkey(u.y, l0 + 1));
        if (u.z != 0xFFFFFFFFu) k2 = umax64(k2, mkkey(u.z, l0 + 2));
        if (u.w != 0xFFFFFFFFu) k2 = umax64(k2, mkkey(u.w, l0 + 3));
      }
      #pragma unroll
      for (int off = 32; off > 0; off >>= 1) {
        unsigned long long o =
          (((unsigned long long)(unsigned int)__shfl_down((unsigned int)(k2 >> 32), off)) << 32)
          | (unsigned int)__shfl_down((unsigned int)(k2 & 0xFFFFFFFFu), off);
        if (o > k2) k2 = o;
      }
      if (lane == 0) s_seg[w] = k2;
    }
    __syncthreads();
  }

  if (t < TOPK) {
    int l = s_top[t];
    if ((s_ingr[l >> 6] >> (l & 63)) & 1ull) {     // is_in_gts at winner
      int b = bg >> 6, g = bg & 63;
      atomicOr(&mask64[(size_t)b * LANCH + l], 1ull << g);
    }
  }
}

// ---------------- K2: conflict resolution + assignment + bg score rows ----------------
__global__ __launch_bounds__(256) void k_assign(
    const float* __restrict__ pred_scores,
    const float* __restrict__ pred_bboxes,
    const float* __restrict__ centers,
    const int*   __restrict__ gt_labels,
    const float* __restrict__ gt_bboxes,
    const float* __restrict__ pad_mask,
    unsigned long long* __restrict__ mask64,
    float*       __restrict__ ws_mm,
    float*       __restrict__ ws_mi,
    float*       __restrict__ out_labels,
    float*       __restrict__ out_bboxes,
    float*       __restrict__ out_fg,
    float*       __restrict__ out_scores)
{
  __shared__ GtLds s;
  const int b = blockIdx.y, t = threadIdx.x;
  load_gt(s, b, gt_bboxes, gt_labels, pad_mask, t);
  __syncthreads();
  const int l = blockIdx.x * 256 + t;
  if (l >= LANCH) return;
  const int idx = b * LANCH + l;

  unsigned long long mb = mask64[idx];
  const int sum1 = __popcll(mb);
  if (sum1 == 0) {
    out_labels[idx] = (float)NCLS;
    reinterpret_cast<float4*>(out_bboxes)[idx] = s.box[0];
    out_fg[idx] = 0.f;
    float4* row = reinterpret_cast<float4*>(out_scores + (size_t)idx * NCLS);
    const float4 z = make_float4(0.f, 0.f, 0.f, 0.f);
    #pragma unroll
    for (int c = 0; c < NCLS / 4; ++c) row[c] = z;
    return;
  }

  const float4 pb = reinterpret_cast<const float4*>(pred_bboxes)[(size_t)b * LANCH + l];
  const float2 cc = reinterpret_cast<const float2*>(centers)[l];
  const float pw = pb.z - pb.x, ph = pb.w - pb.y;
  const float pa = pw * ph;
  const float pcx = (pb.x + pb.z) * 0.5f, pcy = (pb.y + pb.w) * 0.5f;
  const float atp = atanf(pw / ph);
  const float* srow = pred_scores + ((size_t)b * LANCH + l) * NCLS;

  unsigned long long fb = mb;
  if (sum1 > 1) {
    float mx = 0.f;
    unsigned long long eq = 0;
    for (int g = 0; g < NGT; ++g) {
      if (s.padf[g] == 0.f) break;
      float io = masked_ciou(pb, pa, pcx, pcy, atp, cc, s.box[g],
                             s.ga[g], s.gcx[g], s.gcy[g], s.atg[g], s.padf[g]);
      if (io > mx)       { mx = io; eq = 1ull << g; }
      else if (io == mx) { eq |= 1ull << g; }
    }
    fb = eq;
    mask64[idx] = eq;
  }

  unsigned long long bits = fb;
  while (bits) {
    int g = __ffsll((unsigned long long)bits) - 1;
    bits &= bits - 1;
    float io = masked_ciou(pb, pa, pcx, pcy, atp, cc, s.box[g],
                           s.ga[g], s.gcx[g], s.gcy[g], s.atg[g], s.padf[g]);
    float t2 = io * io;
    float met = srow[s.lab[g]] * (t2 * t2 * t2);
    atomicMax(reinterpret_cast<int*>(ws_mm + b * NGT + g), __float_as_int(met));
    atomicMax(reinterpret_cast<int*>(ws_mi + b * NGT + g), __float_as_int(io));
  }
  const int first = __ffsll((unsigned long long)fb) - 1;
  out_labels[idx] = (float)s.lab[first];
  reinterpret_cast<float4*>(out_bboxes)[idx] = s.box[first];
  out_fg[idx] = 1.f;
}

// ---------------- K3: dense score rows for foreground anchors ----------------
__global__ __launch_bounds__(256) void k_scores(
    const float* __restrict__ pred_scores,
    const float* __restrict__ pred_bboxes,
    const float* __restrict__ centers,
    const int*   __restrict__ gt_labels,
    const float* __restrict__ gt_bboxes,
    const float* __restrict__ pad_mask,
    const unsigned long long* __restrict__ mask64,
    const float* __restrict__ ws_mm,
    const float* __restrict__ ws_mi,
    float*       __restrict__ out_scores)
{
  __shared__ GtLds s;
  __shared__ float smm[NGT], smi[NGT];
  const int b = blockIdx.y, t = threadIdx.x;
  load_gt(s, b, gt_bboxes, gt_labels, pad_mask, t);
  if (t < NGT) { smm[t] = ws_mm[b * NGT + t]; smi[t] = ws_mi[b * NGT + t]; }
  __syncthreads();
  const int l = blockIdx.x * 256 + t;
  if (l >= LANCH) return;
  const int idx = b * LANCH + l;
  unsigned long long bits = mask64[idx];
  if (bits == 0ull) return;             // bg rows written by k_assign

  const float4 pb = reinterpret_cast<const float4*>(pred_bboxes)[(size_t)b * LANCH + l];
  const float2 cc = reinterpret_cast<const float2*>(centers)[l];
  const float pw = pb.z - pb.x, ph = pb.w - pb.y;
  const float pa = pw * ph;
  const float pcx = (pb.x + pb.z) * 0.5f, pcy = (pb.y + pb.w) * 0.5f;
  const float atp = atanf(pw / ph);
  const float* srow = pred_scores + ((size_t)b * LANCH + l) * NCLS;

  const int first = __ffsll((unsigned long long)bits) - 1;
  const int lab = s.lab[first];
  float norm = 0.f;
  while (bits) {
    int g = __ffsll((unsigned long long)bits) - 1;
    bits &= bits - 1;
    float io = masked_ciou(pb, pa, pcx, pcy, atp, cc, s.box[g],
                           s.ga[g], s.gcx[g], s.gcy[g], s.atg[g], s.padf[g]);
    float t2 = io * io;
    float met = srow[s.lab[g]] * (t2 * t2 * t2);
    norm = fmaxf(norm, met / (smm[g] + 1e-9f) * smi[g]);
  }
  float4* row = reinterpret_cast<float4*>(out_scores + (size_t)idx * NCLS);
  #pragma unroll
  for (int c = 0; c < NCLS / 4; ++c) {
    float4 wv = make_float4(0.f, 0.f, 0.f, 0.f);
    if (lab >= 4 * c && lab < 4 * c + 4) (&wv.x)[lab - 4 * c] = norm;
    row[c] = wv;
  }
}

extern "C" void kernel_launch(void* const* d_in, const int* in_sizes, int n_in,
                              void* d_out, int out_size, void* d_ws, size_t ws_size,
                              hipStream_t stream) {
  const float* pred_scores = (const float*)d_in[0];
  const float* pred_bboxes = (const float*)d_in[1];
  const float* centers     = (const float*)d_in[2];
  const int*   gt_labels   = (const int*)  d_in[3];
  const float* gt_bboxes   = (const float*)d_in[4];
  const float* pad_mask    = (const float*)d_in[5];

  const size_t BNL = (size_t)BATCH * NGT * LANCH;       // 17,203,200
  char* ws = (char*)d_ws;
  float*              ws_met = (float*)ws;                          // 68.8 MB
  unsigned long long* ws_ing = (unsigned long long*)(ws + BNL * 4); // 2048*132*8 = 2.16 MB
  unsigned long long* mask64 = ws_ing + (size_t)BATCH * NGT * NW64; // 268800*8 = 2.15 MB
  float*              ws_mm  = (float*)(mask64 + (size_t)BATCH * LANCH);
  float*              ws_mi  = ws_mm + BATCH * NGT;

  float* out        = (float*)d_out;
  float* out_labels = out;
  float* out_bboxes = out + (size_t)BATCH * LANCH;
  float* out_scores = out + (size_t)BATCH * LANCH * 5;
  float* out_fg     = out + (size_t)BATCH * LANCH * 5 + (size_t)BATCH * LANCH * NCLS;

  dim3 grid(NCHUNK, BATCH);
  k_pairs<<<grid, 256, 0, stream>>>(pred_scores, pred_bboxes, centers,
      gt_labels, gt_bboxes, pad_mask, ws_met, ws_ing, mask64, ws_mm, ws_mi);

  k_topk<<<BATCH * NGT, 256, 0, stream>>>(ws_met, ws_ing, mask64, pad_mask);

  k_assign<<<grid, 256, 0, stream>>>(pred_scores, pred_bboxes, centers,
      gt_labels, gt_bboxes, pad_mask, mask64, ws_mm, ws_mi,
      out_labels, out_bboxes, out_fg, out_scores);

  k_scores<<<grid, 256, 0, stream>>>(pred_scores, pred_bboxes, centers,
      gt_labels, gt_bboxes, pad_mask, mask64, ws_mm, ws_mi, out_scores);
}

// Round 4
// 233.181 us; speedup vs baseline: 1.2229x; 1.2229x over previous
//
#include <hip/hip_runtime.h>

#define BATCH 32
#define LANCH 8400
#define NCLS  80
#define NGT   64
#define TOPK  13
#define NCHUNK 33          // ceil(8400/256)
#define CAP   1792         // max met>0 entries per row (proof: <=1344)
#define NPW   263          // u32 bitmap words covering 8400 anchors

// ---- shared per-block GT data (K2/K3) ----
struct GtLds {
  float4 box[NGT];
  float  ga[NGT], gcx[NGT], gcy[NGT], atg[NGT], padf[NGT];
  int    lab[NGT];
};

__device__ __forceinline__ void load_gt(GtLds& s, int b,
    const float* gt_bboxes, const int* gt_labels, const float* pad_mask, int t)
{
  if (t < NGT) {
    float4 g = reinterpret_cast<const float4*>(gt_bboxes)[b * NGT + t];
    s.box[t] = g;
    float gw = g.z - g.x, gh = g.w - g.y;
    s.ga[t]  = gw * gh;
    s.gcx[t] = (g.x + g.z) * 0.5f;
    s.gcy[t] = (g.y + g.w) * 0.5f;
    s.atg[t] = atanf(gw / gh);
    s.padf[t] = pad_mask[b * NGT + t];
    s.lab[t]  = gt_labels[b * NGT + t];
  }
}

// clipped CIoU — identical expression in all kernels so recompute is bitwise equal
__device__ __forceinline__ float ciou_core(
    float4 pb, float pa, float pcx, float pcy, float atp,
    float4 gb, float ga, float gcx, float gcy, float atg)
{
  float iw = fmaxf(fminf(gb.z, pb.z) - fmaxf(gb.x, pb.x), 0.f);
  float ih = fmaxf(fminf(gb.w, pb.w) - fmaxf(gb.y, pb.y), 0.f);
  float inter = iw * ih;
  float uni   = ga + pa - inter;
  float iou   = inter / uni;
  float wi = fmaxf(fmaxf(gb.z, pb.z) - fminf(gb.x, pb.x), 0.f);
  float hi = fmaxf(fmaxf(gb.w, pb.w) - fminf(gb.y, pb.y), 0.f);
  float diag2 = wi * wi + hi * hi + 1e-7f;
  float dx = gcx - pcx, dy = gcy - pcy;
  float diou = iou - (dx * dx + dy * dy) / diag2;
  float dat = atg - atp;
  float v = 0.40528473456935109f * dat * dat;     // 4/pi^2
  float alpha = v / (1.f - iou + v + 1e-7f);
  return fmaxf(diou - alpha * v, 0.f);            // nan_to_num + clip>=0
}

__device__ __forceinline__ float masked_ciou(
    float4 pb, float pa, float pcx, float pcy, float atp, float2 cc,
    float4 gb, float ga, float gcx, float gcy, float atg, float padf)
{
  float ltrb = fminf(fminf(cc.x - gb.x, cc.y - gb.y),
                     fminf(gb.z - cc.x, gb.w - cc.y));
  if (!(ltrb > 1e-9f) || padf == 0.f) return 0.f;
  return ciou_core(pb, pa, pcx, pcy, atp, gb, ga, gcx, gcy, atg);
}

// ---------------- K1: per-(b,gt) rect-sparse metrics + exact top-13 ----------------
__global__ __launch_bounds__(256) void k_rowtopk(
    const float* __restrict__ pred_scores,
    const float* __restrict__ pred_bboxes,
    const float* __restrict__ centers,
    const int*   __restrict__ gt_labels,
    const float* __restrict__ gt_bboxes,
    const float* __restrict__ pad_mask,
    unsigned long long* __restrict__ mask64)
{
  const int bg = blockIdx.x;
  if (pad_mask[bg] == 0.f) return;          // padded row: contributes nothing
  const int b = bg >> 6, g = bg & 63, t = threadIdx.x;

  __shared__ unsigned long long s_keys[CAP];
  __shared__ unsigned int       s_pos[NPW];   // met>0 bitmap over l
  __shared__ unsigned long long s_red[4];
  __shared__ unsigned long long s_kill;
  __shared__ int s_winl[TOPK];
  __shared__ int s_cnt;

  for (int i = t; i < NPW; i += 256) s_pos[i] = (i == NPW - 1) ? 0xFFFF0000u : 0u;
  if (t == 0) s_cnt = 0;

  const float4 gt = reinterpret_cast<const float4*>(gt_bboxes)[bg];
  const int   lab = gt_labels[bg];
  const float gw = gt.z - gt.x, gh = gt.w - gt.y;
  const float ga = gw * gh;
  const float gcx = (gt.x + gt.z) * 0.5f, gcy = (gt.y + gt.w) * 0.5f;
  const float atg = atanf(gw / gh);

  // conservative integer rects per scale (exact float test applied per candidate)
  const int gdim[3] = {80, 40, 20};
  const int base[3] = {0, 6400, 8000};
  const float inv[3] = {0.125f, 0.0625f, 0.03125f};
  int i0[3], j0[3], w_[3], cum[4]; cum[0] = 0;
  for (int k = 0; k < 3; ++k) {
    int a0 = (int)floorf(gt.x * inv[k] - 0.5f) - 1; a0 = a0 < 0 ? 0 : a0;
    int a1 = (int)ceilf (gt.z * inv[k] - 0.5f) + 1; a1 = a1 > gdim[k] - 1 ? gdim[k] - 1 : a1;
    int b0 = (int)floorf(gt.y * inv[k] - 0.5f) - 1; b0 = b0 < 0 ? 0 : b0;
    int b1 = (int)ceilf (gt.w * inv[k] - 0.5f) + 1; b1 = b1 > gdim[k] - 1 ? gdim[k] - 1 : b1;
    i0[k] = a0; j0[k] = b0;
    int ww = a1 >= a0 ? a1 - a0 + 1 : 0;
    int hh = b1 >= b0 ? b1 - b0 + 1 : 0;
    w_[k] = ww;
    cum[k + 1] = cum[k] + ww * hh;
  }
  const int total = cum[3];
  const float2* cc2 = reinterpret_cast<const float2*>(centers);
  const float4* pb4 = reinterpret_cast<const float4*>(pred_bboxes) + (size_t)b * LANCH;
  const float*  sc  = pred_scores + (size_t)b * LANCH * NCLS + lab;
  __syncthreads();

  for (int c = t; c < total; c += 256) {
    int k = (c >= cum[1]) + (c >= cum[2]);
    int r = c - cum[k];
    int di = r % w_[k], dj = r / w_[k];
    int l = base[k] + (j0[k] + dj) * gdim[k] + (i0[k] + di);
    float2 cc = cc2[l];
    float ltrb = fminf(fminf(cc.x - gt.x, cc.y - gt.y),
                       fminf(gt.z - cc.x, gt.w - cc.y));
    if (!(ltrb > 1e-9f)) continue;          // exact reference test
    float4 pb = pb4[l];
    float pw = pb.z - pb.x, ph = pb.w - pb.y, pa = pw * ph;
    float pcx = (pb.x + pb.z) * 0.5f, pcy = (pb.y + pb.w) * 0.5f;
    float atp = atanf(pw / ph);
    float io = ciou_core(pb, pa, pcx, pcy, atp, gt, ga, gcx, gcy, atg);
    float t2 = io * io;
    float met = sc[(size_t)l * NCLS] * (t2 * t2 * t2);
    if (met > 0.f) {
      int idx = atomicAdd(&s_cnt, 1);
      s_keys[idx] = ((unsigned long long)__float_as_uint(met) << 32)
                  | (unsigned int)(0x7FFFFFFF - l);       // desc met, asc idx
      atomicOr(&s_pos[l >> 5], 1u << (l & 31));
    }
  }
  __syncthreads();
  const int nnz  = s_cnt;
  const int npos = nnz < TOPK ? nnz : TOPK;
  const int w = t >> 6, lane = t & 63;

  unsigned long long mybest = 0;
  for (int i = t; i < nnz; i += 256) { unsigned long long v = s_keys[i]; if (v > mybest) mybest = v; }

  for (int it = 0; it < npos; ++it) {
    unsigned long long k = mybest;
    #pragma unroll
    for (int off = 32; off > 0; off >>= 1) {
      unsigned long long o = __shfl_down(k, off);
      if (o > k) k = o;
    }
    if (lane == 0) s_red[w] = k;
    __syncthreads();
    if (t == 0) {
      unsigned long long kk = s_red[0];
      if (s_red[1] > kk) kk = s_red[1];
      if (s_red[2] > kk) kk = s_red[2];
      if (s_red[3] > kk) kk = s_red[3];
      s_kill = kk;
      s_winl[it] = 0x7FFFFFFF - (int)(unsigned int)(kk & 0xFFFFFFFFu);
    }
    __syncthreads();
    unsigned long long kk = s_kill;
    bool own = false;
    for (int i = t; i < nnz; i += 256)
      if (s_keys[i] == kk) { s_keys[i] = 0; own = true; }
    if (own) {
      mybest = 0;
      for (int i = t; i < nnz; i += 256) { unsigned long long v = s_keys[i]; if (v > mybest) mybest = v; }
    }
    __syncthreads();
  }
  if (t == 0 && npos < TOPK) {
    // fill with smallest-index met==0 anchors (jax.lax.top_k tie-break)
    int found = npos;
    for (int wd = 0; wd < NPW && found < TOPK; ++wd) {
      unsigned int z = ~s_pos[wd];
      while (z && found < TOPK) {
        int bit = __ffs(z) - 1; z &= z - 1;
        s_winl[found++] = wd * 32 + bit;
      }
    }
  }
  __syncthreads();
  if (t < TOPK) {
    int l = s_winl[t];
    float2 cc = cc2[l];
    float ltrb = fminf(fminf(cc.x - gt.x, cc.y - gt.y),
                       fminf(gt.z - cc.x, gt.w - cc.y));
    if (ltrb > 1e-9f)                       // winner's is_in_gts
      atomicOr(&mask64[(size_t)b * LANCH + l], 1ull << g);
  }
}

// ---------------- K2: conflict resolution + assignment + bg score rows ----------------
__global__ __launch_bounds__(256) void k_assign(
    const float* __restrict__ pred_scores,
    const float* __restrict__ pred_bboxes,
    const float* __restrict__ centers,
    const int*   __restrict__ gt_labels,
    const float* __restrict__ gt_bboxes,
    const float* __restrict__ pad_mask,
    unsigned long long* __restrict__ mask64,
    float*       __restrict__ ws_mm,
    float*       __restrict__ ws_mi,
    float*       __restrict__ out_labels,
    float*       __restrict__ out_bboxes,
    float*       __restrict__ out_fg,
    float*       __restrict__ out_scores)
{
  __shared__ GtLds s;
  const int b = blockIdx.y, t = threadIdx.x;
  load_gt(s, b, gt_bboxes, gt_labels, pad_mask, t);
  __syncthreads();
  const int l = blockIdx.x * 256 + t;
  if (l >= LANCH) return;
  const int idx = b * LANCH + l;

  unsigned long long mb = mask64[idx];
  const int sum1 = __popcll(mb);
  if (sum1 == 0) {
    out_labels[idx] = (float)NCLS;
    reinterpret_cast<float4*>(out_bboxes)[idx] = s.box[0];
    out_fg[idx] = 0.f;
    float4* row = reinterpret_cast<float4*>(out_scores + (size_t)idx * NCLS);
    const float4 z = make_float4(0.f, 0.f, 0.f, 0.f);
    #pragma unroll
    for (int c = 0; c < NCLS / 4; ++c) row[c] = z;
    return;
  }

  const float4 pb = reinterpret_cast<const float4*>(pred_bboxes)[(size_t)b * LANCH + l];
  const float2 cc = reinterpret_cast<const float2*>(centers)[l];
  const float pw = pb.z - pb.x, ph = pb.w - pb.y;
  const float pa = pw * ph;
  const float pcx = (pb.x + pb.z) * 0.5f, pcy = (pb.y + pb.w) * 0.5f;
  const float atp = atanf(pw / ph);
  const float* srow = pred_scores + ((size_t)b * LANCH + l) * NCLS;

  unsigned long long fb = mb;
  if (sum1 > 1) {
    float mx = 0.f;
    unsigned long long eq = 0;
    for (int g = 0; g < NGT; ++g) {
      if (s.padf[g] == 0.f) break;          // pad is a prefix
      float io = masked_ciou(pb, pa, pcx, pcy, atp, cc, s.box[g],
                             s.ga[g], s.gcx[g], s.gcy[g], s.atg[g], s.padf[g]);
      if (io > mx)       { mx = io; eq = 1ull << g; }
      else if (io == mx) { eq |= 1ull << g; }
    }
    fb = eq;
    mask64[idx] = eq;
  }

  unsigned long long bits = fb;
  while (bits) {
    int g = __ffsll((unsigned long long)bits) - 1;
    bits &= bits - 1;
    float io = masked_ciou(pb, pa, pcx, pcy, atp, cc, s.box[g],
                           s.ga[g], s.gcx[g], s.gcy[g], s.atg[g], s.padf[g]);
    float t2 = io * io;
    float met = srow[s.lab[g]] * (t2 * t2 * t2);
    atomicMax(reinterpret_cast<int*>(ws_mm + b * NGT + g), __float_as_int(met));
    atomicMax(reinterpret_cast<int*>(ws_mi + b * NGT + g), __float_as_int(io));
  }
  const int first = __ffsll((unsigned long long)fb) - 1;
  out_labels[idx] = (float)s.lab[first];
  reinterpret_cast<float4*>(out_bboxes)[idx] = s.box[first];
  out_fg[idx] = 1.f;
}

// ---------------- K3: dense score rows for foreground anchors ----------------
__global__ __launch_bounds__(256) void k_scores(
    const float* __restrict__ pred_scores,
    const float* __restrict__ pred_bboxes,
    const float* __restrict__ centers,
    const int*   __restrict__ gt_labels,
    const float* __restrict__ gt_bboxes,
    const float* __restrict__ pad_mask,
    const unsigned long long* __restrict__ mask64,
    const float* __restrict__ ws_mm,
    const float* __restrict__ ws_mi,
    float*       __restrict__ out_scores)
{
  __shared__ GtLds s;
  __shared__ float smm[NGT], smi[NGT];
  const int b = blockIdx.y, t = threadIdx.x;
  load_gt(s, b, gt_bboxes, gt_labels, pad_mask, t);
  if (t < NGT) { smm[t] = ws_mm[b * NGT + t]; smi[t] = ws_mi[b * NGT + t]; }
  __syncthreads();
  const int l = blockIdx.x * 256 + t;
  if (l >= LANCH) return;
  const int idx = b * LANCH + l;
  unsigned long long bits = mask64[idx];
  if (bits == 0ull) return;               // bg rows written by k_assign

  const float4 pb = reinterpret_cast<const float4*>(pred_bboxes)[(size_t)b * LANCH + l];
  const float2 cc = reinterpret_cast<const float2*>(centers)[l];
  const float pw = pb.z - pb.x, ph = pb.w - pb.y;
  const float pa = pw * ph;
  const float pcx = (pb.x + pb.z) * 0.5f, pcy = (pb.y + pb.w) * 0.5f;
  const float atp = atanf(pw / ph);
  const float* srow = pred_scores + ((size_t)b * LANCH + l) * NCLS;

  const int first = __ffsll((unsigned long long)bits) - 1;
  const int lab = s.lab[first];
  float norm = 0.f;
  while (bits) {
    int g = __ffsll((unsigned long long)bits) - 1;
    bits &= bits - 1;
    float io = masked_ciou(pb, pa, pcx, pcy, atp, cc, s.box[g],
                           s.ga[g], s.gcx[g], s.gcy[g], s.atg[g], s.padf[g]);
    float t2 = io * io;
    float met = srow[s.lab[g]] * (t2 * t2 * t2);
    norm = fmaxf(norm, met / (smm[g] + 1e-9f) * smi[g]);
  }
  float4* row = reinterpret_cast<float4*>(out_scores + (size_t)idx * NCLS);
  #pragma unroll
  for (int c = 0; c < NCLS / 4; ++c) {
    float4 wv = make_float4(0.f, 0.f, 0.f, 0.f);
    if (lab >= 4 * c && lab < 4 * c + 4) (&wv.x)[lab - 4 * c] = norm;
    row[c] = wv;
  }
}

extern "C" void kernel_launch(void* const* d_in, const int* in_sizes, int n_in,
                              void* d_out, int out_size, void* d_ws, size_t ws_size,
                              hipStream_t stream) {
  const float* pred_scores = (const float*)d_in[0];
  const float* pred_bboxes = (const float*)d_in[1];
  const float* centers     = (const float*)d_in[2];
  const int*   gt_labels   = (const int*)  d_in[3];
  const float* gt_bboxes   = (const float*)d_in[4];
  const float* pad_mask    = (const float*)d_in[5];

  char* ws = (char*)d_ws;
  unsigned long long* mask64 = (unsigned long long*)ws;             // 268800*8 = 2.15 MB
  float* ws_mm = (float*)(ws + (size_t)BATCH * LANCH * 8);          // 2048 f32
  float* ws_mi = ws_mm + BATCH * NGT;                               // 2048 f32
  const size_t zero_bytes = (size_t)BATCH * LANCH * 8 + 2 * BATCH * NGT * sizeof(float);

  float* out        = (float*)d_out;
  float* out_labels = out;
  float* out_bboxes = out + (size_t)BATCH * LANCH;
  float* out_scores = out + (size_t)BATCH * LANCH * 5;
  float* out_fg     = out + (size_t)BATCH * LANCH * 5 + (size_t)BATCH * LANCH * NCLS;

  hipMemsetAsync(ws, 0, zero_bytes, stream);   // mask64 + mm + mi

  k_rowtopk<<<BATCH * NGT, 256, 0, stream>>>(pred_scores, pred_bboxes, centers,
      gt_labels, gt_bboxes, pad_mask, mask64);

  dim3 grid(NCHUNK, BATCH);
  k_assign<<<grid, 256, 0, stream>>>(pred_scores, pred_bboxes, centers,
      gt_labels, gt_bboxes, pad_mask, mask64, ws_mm, ws_mi,
      out_labels, out_bboxes, out_fg, out_scores);

  k_scores<<<grid, 256, 0, stream>>>(pred_scores, pred_bboxes, centers,
      gt_labels, gt_bboxes, pad_mask, mask64, ws_mm, ws_mi, out_scores);
}

// Round 5
// 226.974 us; speedup vs baseline: 1.2563x; 1.0273x over previous
//
#include <hip/hip_runtime.h>

#define BATCH 32
#define LANCH 8400
#define NCLS  80
#define NGT   64
#define TOPK  13
#define NCHUNK 33          // ceil(8400/256)
#define CAP   1792         // max met>0 entries per row (proof: <=1344)
#define NPW   263          // u32 bitmap words covering 8400 anchors

// ---- shared per-block GT data ----
struct GtLds {
  float4 box[NGT];
  float  ga[NGT], gcx[NGT], gcy[NGT], atg[NGT], padf[NGT];
  int    lab[NGT];
};

__device__ __forceinline__ void load_gt(GtLds& s, int b,
    const float* gt_bboxes, const int* gt_labels, const float* pad_mask, int t)
{
  if (t < NGT) {
    float4 g = reinterpret_cast<const float4*>(gt_bboxes)[b * NGT + t];
    s.box[t] = g;
    float gw = g.z - g.x, gh = g.w - g.y;
    s.ga[t]  = gw * gh;
    s.gcx[t] = (g.x + g.z) * 0.5f;
    s.gcy[t] = (g.y + g.w) * 0.5f;
    s.atg[t] = atanf(gw / gh);
    s.padf[t] = pad_mask[b * NGT + t];
    s.lab[t]  = gt_labels[b * NGT + t];
  }
}

// clipped CIoU — identical expression in all kernels so recompute is bitwise equal
__device__ __forceinline__ float ciou_core(
    float4 pb, float pa, float pcx, float pcy, float atp,
    float4 gb, float ga, float gcx, float gcy, float atg)
{
  float iw = fmaxf(fminf(gb.z, pb.z) - fmaxf(gb.x, pb.x), 0.f);
  float ih = fmaxf(fminf(gb.w, pb.w) - fmaxf(gb.y, pb.y), 0.f);
  float inter = iw * ih;
  float uni   = ga + pa - inter;
  float iou   = inter / uni;
  float wi = fmaxf(fmaxf(gb.z, pb.z) - fminf(gb.x, pb.x), 0.f);
  float hi = fmaxf(fmaxf(gb.w, pb.w) - fminf(gb.y, pb.y), 0.f);
  float diag2 = wi * wi + hi * hi + 1e-7f;
  float dx = gcx - pcx, dy = gcy - pcy;
  float diou = iou - (dx * dx + dy * dy) / diag2;
  float dat = atg - atp;
  float v = 0.40528473456935109f * dat * dat;     // 4/pi^2
  float alpha = v / (1.f - iou + v + 1e-7f);
  return fmaxf(diou - alpha * v, 0.f);            // nan_to_num + clip>=0
}

__device__ __forceinline__ float masked_ciou(
    float4 pb, float pa, float pcx, float pcy, float atp, float2 cc,
    float4 gb, float ga, float gcx, float gcy, float atg, float padf)
{
  float ltrb = fminf(fminf(cc.x - gb.x, cc.y - gb.y),
                     fminf(gb.z - cc.x, gb.w - cc.y));
  if (!(ltrb > 1e-9f) || padf == 0.f) return 0.f;
  return ciou_core(pb, pa, pcx, pcy, atp, gb, ga, gcx, gcy, atg);
}

// ---------------- K1: per-(b,gt) rect-sparse metrics + exact top-13 ----------------
__global__ __launch_bounds__(256) void k_rowtopk(
    const float* __restrict__ pred_scores,
    const float* __restrict__ pred_bboxes,
    const float* __restrict__ centers,
    const int*   __restrict__ gt_labels,
    const float* __restrict__ gt_bboxes,
    const float* __restrict__ pad_mask,
    unsigned long long* __restrict__ mask64)
{
  const int bg = blockIdx.x;
  if (pad_mask[bg] == 0.f) return;
  const int b = bg >> 6, g = bg & 63, t = threadIdx.x;

  __shared__ unsigned long long s_keys[CAP];
  __shared__ unsigned int       s_pos[NPW];
  __shared__ unsigned long long s_red[4];
  __shared__ unsigned long long s_kill;
  __shared__ int s_winl[TOPK];
  __shared__ int s_cnt;

  for (int i = t; i < NPW; i += 256) s_pos[i] = (i == NPW - 1) ? 0xFFFF0000u : 0u;
  if (t == 0) s_cnt = 0;

  const float4 gt = reinterpret_cast<const float4*>(gt_bboxes)[bg];
  const int   lab = gt_labels[bg];
  const float gw = gt.z - gt.x, gh = gt.w - gt.y;
  const float ga = gw * gh;
  const float gcx = (gt.x + gt.z) * 0.5f, gcy = (gt.y + gt.w) * 0.5f;
  const float atg = atanf(gw / gh);

  const int gdim[3] = {80, 40, 20};
  const int base[3] = {0, 6400, 8000};
  const float inv[3] = {0.125f, 0.0625f, 0.03125f};
  int i0[3], j0[3], w_[3], cum[4]; cum[0] = 0;
  for (int k = 0; k < 3; ++k) {
    int a0 = (int)floorf(gt.x * inv[k] - 0.5f) - 1; a0 = a0 < 0 ? 0 : a0;
    int a1 = (int)ceilf (gt.z * inv[k] - 0.5f) + 1; a1 = a1 > gdim[k] - 1 ? gdim[k] - 1 : a1;
    int b0 = (int)floorf(gt.y * inv[k] - 0.5f) - 1; b0 = b0 < 0 ? 0 : b0;
    int b1 = (int)ceilf (gt.w * inv[k] - 0.5f) + 1; b1 = b1 > gdim[k] - 1 ? gdim[k] - 1 : b1;
    i0[k] = a0; j0[k] = b0;
    int ww = a1 >= a0 ? a1 - a0 + 1 : 0;
    int hh = b1 >= b0 ? b1 - b0 + 1 : 0;
    w_[k] = ww;
    cum[k + 1] = cum[k] + ww * hh;
  }
  const int total = cum[3];
  const float2* cc2 = reinterpret_cast<const float2*>(centers);
  const float4* pb4 = reinterpret_cast<const float4*>(pred_bboxes) + (size_t)b * LANCH;
  const float*  sc  = pred_scores + (size_t)b * LANCH * NCLS + lab;
  __syncthreads();

  for (int c = t; c < total; c += 256) {
    int k = (c >= cum[1]) + (c >= cum[2]);
    int r = c - cum[k];
    int di = r % w_[k], dj = r / w_[k];
    int l = base[k] + (j0[k] + dj) * gdim[k] + (i0[k] + di);
    float2 cc = cc2[l];
    float ltrb = fminf(fminf(cc.x - gt.x, cc.y - gt.y),
                       fminf(gt.z - cc.x, gt.w - cc.y));
    if (!(ltrb > 1e-9f)) continue;
    float4 pb = pb4[l];
    float pw = pb.z - pb.x, ph = pb.w - pb.y, pa = pw * ph;
    float pcx = (pb.x + pb.z) * 0.5f, pcy = (pb.y + pb.w) * 0.5f;
    float atp = atanf(pw / ph);
    float io = ciou_core(pb, pa, pcx, pcy, atp, gt, ga, gcx, gcy, atg);
    float t2 = io * io;
    float met = sc[(size_t)l * NCLS] * (t2 * t2 * t2);
    if (met > 0.f) {
      int idx = atomicAdd(&s_cnt, 1);
      s_keys[idx] = ((unsigned long long)__float_as_uint(met) << 32)
                  | (unsigned int)(0x7FFFFFFF - l);       // desc met, asc idx
      atomicOr(&s_pos[l >> 5], 1u << (l & 31));
    }
  }
  __syncthreads();
  const int nnz  = s_cnt;
  const int npos = nnz < TOPK ? nnz : TOPK;
  const int w = t >> 6, lane = t & 63;

  unsigned long long mybest = 0;
  for (int i = t; i < nnz; i += 256) { unsigned long long v = s_keys[i]; if (v > mybest) mybest = v; }

  for (int it = 0; it < npos; ++it) {
    unsigned long long k = mybest;
    #pragma unroll
    for (int off = 32; off > 0; off >>= 1) {
      unsigned long long o = __shfl_down(k, off);
      if (o > k) k = o;
    }
    if (lane == 0) s_red[w] = k;
    __syncthreads();
    if (t == 0) {
      unsigned long long kk = s_red[0];
      if (s_red[1] > kk) kk = s_red[1];
      if (s_red[2] > kk) kk = s_red[2];
      if (s_red[3] > kk) kk = s_red[3];
      s_kill = kk;
      s_winl[it] = 0x7FFFFFFF - (int)(unsigned int)(kk & 0xFFFFFFFFu);
    }
    __syncthreads();
    unsigned long long kk = s_kill;
    bool own = false;
    for (int i = t; i < nnz; i += 256)
      if (s_keys[i] == kk) { s_keys[i] = 0; own = true; }
    if (own) {
      mybest = 0;
      for (int i = t; i < nnz; i += 256) { unsigned long long v = s_keys[i]; if (v > mybest) mybest = v; }
    }
    __syncthreads();
  }
  if (t == 0 && npos < TOPK) {
    int found = npos;
    for (int wd = 0; wd < NPW && found < TOPK; ++wd) {
      unsigned int z = ~s_pos[wd];
      while (z && found < TOPK) {
        int bit = __ffs(z) - 1; z &= z - 1;
        s_winl[found++] = wd * 32 + bit;
      }
    }
  }
  __syncthreads();
  if (t < TOPK) {
    int l = s_winl[t];
    float2 cc = cc2[l];
    float ltrb = fminf(fminf(cc.x - gt.x, cc.y - gt.y),
                       fminf(gt.z - cc.x, gt.w - cc.y));
    if (ltrb > 1e-9f)
      atomicOr(&mask64[(size_t)b * LANCH + l], 1ull << g);
  }
}

// ------- K2: SPARSE conflict resolution + per-gt maxima (no output writes) -------
__global__ __launch_bounds__(256) void k_resolve(
    const float* __restrict__ pred_scores,
    const float* __restrict__ pred_bboxes,
    const float* __restrict__ centers,
    const int*   __restrict__ gt_labels,
    const float* __restrict__ gt_bboxes,
    const float* __restrict__ pad_mask,
    unsigned long long* __restrict__ mask64,
    float*       __restrict__ ws_mm,
    float*       __restrict__ ws_mi)
{
  __shared__ GtLds s;
  const int b = blockIdx.y, t = threadIdx.x;
  load_gt(s, b, gt_bboxes, gt_labels, pad_mask, t);
  __syncthreads();
  const int l = blockIdx.x * 256 + t;
  if (l >= LANCH) return;
  const int idx = b * LANCH + l;

  unsigned long long mb = mask64[idx];
  if (mb == 0ull) return;                 // ~97% of anchors
  const int sum1 = __popcll(mb);

  const float4 pb = reinterpret_cast<const float4*>(pred_bboxes)[(size_t)b * LANCH + l];
  const float2 cc = reinterpret_cast<const float2*>(centers)[l];
  const float pw = pb.z - pb.x, ph = pb.w - pb.y;
  const float pa = pw * ph;
  const float pcx = (pb.x + pb.z) * 0.5f, pcy = (pb.y + pb.w) * 0.5f;
  const float atp = atanf(pw / ph);
  const float* srow = pred_scores + ((size_t)b * LANCH + l) * NCLS;

  unsigned long long fb = mb;
  if (sum1 > 1) {
    float mx = 0.f;
    unsigned long long eq = 0;
    for (int g = 0; g < NGT; ++g) {
      if (s.padf[g] == 0.f) break;        // pad is a prefix
      float io = masked_ciou(pb, pa, pcx, pcy, atp, cc, s.box[g],
                             s.ga[g], s.gcx[g], s.gcy[g], s.atg[g], s.padf[g]);
      if (io > mx)       { mx = io; eq = 1ull << g; }
      else if (io == mx) { eq |= 1ull << g; }
    }
    fb = eq;
    mask64[idx] = eq;
  }

  unsigned long long bits = fb;
  while (bits) {
    int g = __ffsll((unsigned long long)bits) - 1;
    bits &= bits - 1;
    float io = masked_ciou(pb, pa, pcx, pcy, atp, cc, s.box[g],
                           s.ga[g], s.gcx[g], s.gcy[g], s.atg[g], s.padf[g]);
    float t2 = io * io;
    float met = srow[s.lab[g]] * (t2 * t2 * t2);
    atomicMax(reinterpret_cast<int*>(ws_mm + b * NGT + g), __float_as_int(met));
    atomicMax(reinterpret_cast<int*>(ws_mi + b * NGT + g), __float_as_int(io));
  }
}

// ---------- K3: single DENSE writer — labels/bboxes/fg + coalesced score tile ----------
__global__ __launch_bounds__(256) void k_write(
    const float* __restrict__ pred_scores,
    const float* __restrict__ pred_bboxes,
    const float* __restrict__ centers,
    const int*   __restrict__ gt_labels,
    const float* __restrict__ gt_bboxes,
    const float* __restrict__ pad_mask,
    const unsigned long long* __restrict__ mask64,
    const float* __restrict__ ws_mm,
    const float* __restrict__ ws_mi,
    float*       __restrict__ out_labels,
    float*       __restrict__ out_bboxes,
    float*       __restrict__ out_fg,
    float*       __restrict__ out_scores)
{
  __shared__ GtLds s;
  __shared__ float smm[NGT], smi[NGT];
  __shared__ float s_norm[256];
  __shared__ int   s_lab[256];
  const int b = blockIdx.y, t = threadIdx.x;
  load_gt(s, b, gt_bboxes, gt_labels, pad_mask, t);
  if (t < NGT) { smm[t] = ws_mm[b * NGT + t]; smi[t] = ws_mi[b * NGT + t]; }
  __syncthreads();
  const int l0 = blockIdx.x * 256;
  const int l  = l0 + t;
  const bool act = (l < LANCH);

  float norm = 0.f;
  int   lab  = NCLS;
  if (act) {
    const int idx = b * LANCH + l;
    unsigned long long bits = mask64[idx];
    if (bits != 0ull) {
      const float4 pb = reinterpret_cast<const float4*>(pred_bboxes)[(size_t)b * LANCH + l];
      const float2 cc = reinterpret_cast<const float2*>(centers)[l];
      const float pw = pb.z - pb.x, ph = pb.w - pb.y;
      const float pa = pw * ph;
      const float pcx = (pb.x + pb.z) * 0.5f, pcy = (pb.y + pb.w) * 0.5f;
      const float atp = atanf(pw / ph);
      const float* srow = pred_scores + ((size_t)b * LANCH + l) * NCLS;
      const int first = __ffsll((unsigned long long)bits) - 1;
      lab = s.lab[first];
      unsigned long long bb = bits;
      while (bb) {
        int g = __ffsll((unsigned long long)bb) - 1;
        bb &= bb - 1;
        float io = masked_ciou(pb, pa, pcx, pcy, atp, cc, s.box[g],
                               s.ga[g], s.gcx[g], s.gcy[g], s.atg[g], s.padf[g]);
        float t2 = io * io;
        float met = srow[s.lab[g]] * (t2 * t2 * t2);
        norm = fmaxf(norm, met / (smm[g] + 1e-9f) * smi[g]);
      }
      out_labels[idx] = (float)lab;
      reinterpret_cast<float4*>(out_bboxes)[idx] = s.box[first];
      out_fg[idx] = 1.f;
    } else {
      out_labels[idx] = (float)NCLS;
      reinterpret_cast<float4*>(out_bboxes)[idx] = s.box[0];
      out_fg[idx] = 0.f;
    }
  }
  s_norm[t] = norm;
  s_lab[t]  = lab;          // NCLS for bg -> never matches a slot
  __syncthreads();

  // cooperative coalesced write of the 256x80 score tile (float4 granularity)
  const int QC = NCLS / 4;                       // 20 float4 columns
  float4* tile = reinterpret_cast<float4*>(out_scores + ((size_t)b * LANCH + l0) * NCLS);
  const int amax = (LANCH - l0) < 256 ? (LANCH - l0) : 256;
  #pragma unroll
  for (int k = 0; k < QC; ++k) {
    int p = k * 256 + t;                         // tile float4 index
    int a = p / QC, c4 = p - a * QC;             // anchor row, float4 col
    if (a < amax) {
      float4 wv = make_float4(0.f, 0.f, 0.f, 0.f);
      int la = s_lab[a], base = c4 * 4;
      if (la >= base && la < base + 4) (&wv.x)[la - base] = s_norm[a];
      tile[p] = wv;
    }
  }
}

extern "C" void kernel_launch(void* const* d_in, const int* in_sizes, int n_in,
                              void* d_out, int out_size, void* d_ws, size_t ws_size,
                              hipStream_t stream) {
  const float* pred_scores = (const float*)d_in[0];
  const float* pred_bboxes = (const float*)d_in[1];
  const float* centers     = (const float*)d_in[2];
  const int*   gt_labels   = (const int*)  d_in[3];
  const float* gt_bboxes   = (const float*)d_in[4];
  const float* pad_mask    = (const float*)d_in[5];

  char* ws = (char*)d_ws;
  unsigned long long* mask64 = (unsigned long long*)ws;             // 2.15 MB
  float* ws_mm = (float*)(ws + (size_t)BATCH * LANCH * 8);
  float* ws_mi = ws_mm + BATCH * NGT;
  const size_t zero_bytes = (size_t)BATCH * LANCH * 8 + 2 * BATCH * NGT * sizeof(float);

  float* out        = (float*)d_out;
  float* out_labels = out;
  float* out_bboxes = out + (size_t)BATCH * LANCH;
  float* out_scores = out + (size_t)BATCH * LANCH * 5;
  float* out_fg     = out + (size_t)BATCH * LANCH * 5 + (size_t)BATCH * LANCH * NCLS;

  hipMemsetAsync(ws, 0, zero_bytes, stream);   // mask64 + mm + mi

  k_rowtopk<<<BATCH * NGT, 256, 0, stream>>>(pred_scores, pred_bboxes, centers,
      gt_labels, gt_bboxes, pad_mask, mask64);

  dim3 grid(NCHUNK, BATCH);
  k_resolve<<<grid, 256, 0, stream>>>(pred_scores, pred_bboxes, centers,
      gt_labels, gt_bboxes, pad_mask, mask64, ws_mm, ws_mi);

  k_write<<<grid, 256, 0, stream>>>(pred_scores, pred_bboxes, centers,
      gt_labels, gt_bboxes, pad_mask, mask64, ws_mm, ws_mi,
      out_labels, out_bboxes, out_fg, out_scores);
}